// Round 6
// baseline (117.457 us; speedup 1.0000x reference)
//
#include <hip/hip_runtime.h>
#include <utility>

// OctreeConv: out[N,64] = sum_k gather_k(input)[N,32] @ W[k][32,64]
// Round 6: inline-asm forced gather pipeline. The compiler kept collapsing
// the software pipeline to ~4 deep (R3/R5: VGPR=88/52); here the 16-deep
// rotating buffer is built from asm-volatile global_load_dwordx4 + counted
// s_waitcnt vmcnt(N), with the consumed register pinned "+v" into the wait
// (rule #18) so MFMA cannot hoist above it. 16 waves/CU x 16 in flight.

typedef float  f32x4  __attribute__((ext_vector_type(4)));
typedef __bf16 bf16x8 __attribute__((ext_vector_type(8)));
typedef int    i32x4  __attribute__((ext_vector_type(4)));
typedef ushort u16x4  __attribute__((ext_vector_type(4)));
typedef ushort u16x8  __attribute__((ext_vector_type(8)));

#define NN 262144
#define CI 32
#define CO 64
#define KK 27
#define THREADS 1024
#define PF 16                 // forced prefetch depth (taps in flight)
#define OCT_PER_BLOCK 256     // 16 waves x 16 octants

__device__ __forceinline__ ushort f2bf_rne(float f) {
  union { float f; unsigned u; } v; v.f = f;
  unsigned u = v.u;
  u += 0x7FFFu + ((u >> 16) & 1u);
  return (ushort)(u >> 16);
}

// fp32 -> bf16 pre-pass; last block writes a zero row at index NN
// (gather target for invalid neighbors).
__global__ __launch_bounds__(256) void cvt_input_kernel(
    const float* __restrict__ in, ushort* __restrict__ out) {
  const int bid = blockIdx.x;
  if (bid == (NN * CI) / 1024) {
    if (threadIdx.x < 8) {
      u16x4 z = {0, 0, 0, 0};
      *(u16x4*)(out + (size_t)NN * CI + threadIdx.x * 4) = z;
    }
    return;
  }
  const int i = (bid * 256 + threadIdx.x) * 4;
  f32x4 v = *(const f32x4*)(in + i);
  u16x4 o;
  o[0] = f2bf_rne(v[0]); o[1] = f2bf_rne(v[1]);
  o[2] = f2bf_rne(v[2]); o[3] = f2bf_rne(v[3]);
  *(u16x4*)(out + i) = o;
}

// asm gather: 16B load, base(SGPR pair) + u32 voffset. asm volatile keeps
// issue order and prevents the compiler from sinking/shrinking the pipeline.
__device__ __forceinline__ void gload16(i32x4& dst, uint32_t voff,
                                        const char* base) {
  asm volatile("global_load_dwordx4 %0, %1, %2"
               : "=v"(dst)
               : "v"(voff), "s"(base));
}

// counted wait; "+v" on the consumed value makes every later use (the MFMA)
// data-dependent on the wait -> cannot be scheduled above it.
template <int N>
__device__ __forceinline__ void wait_vmcnt_pin(i32x4& v) {
  asm volatile("s_waitcnt vmcnt(%1)" : "+v"(v) : "n"(N));
}

template <int K>
__device__ __forceinline__ void tap(i32x4 (&abuf)[PF],
                                    const uint32_t (&voff)[KK],
                                    const char* ibase,
                                    const ushort* __restrict__ wfrag,
                                    f32x4 (&acc)[4]) {
  constexpr int NWAIT = (PF - 1 < KK - 1 - K) ? (PF - 1) : (KK - 1 - K);
  wait_vmcnt_pin<NWAIT>(abuf[K % PF]);
  const bf16x8 a = __builtin_bit_cast(bf16x8, abuf[K % PF]);
#pragma unroll
  for (int b = 0; b < 4; ++b) {
    const bf16x8 bf = *(const bf16x8*)(wfrag + K * 2048 + b * 128);
    acc[b] = __builtin_amdgcn_mfma_f32_16x16x32_bf16(a, bf, acc[b], 0, 0, 0);
  }
  if constexpr (K + PF < KK)
    gload16(abuf[K % PF], voff[K + PF], ibase);
}

template <size_t... Ks>
__device__ __forceinline__ void run_taps(std::index_sequence<Ks...>,
                                         i32x4 (&abuf)[PF],
                                         const uint32_t (&voff)[KK],
                                         const char* ibase,
                                         const ushort* __restrict__ wfrag,
                                         f32x4 (&acc)[4]) {
  (tap<(int)Ks>(abuf, voff, ibase, wfrag, acc), ...);
}

__global__ __launch_bounds__(THREADS, 4) void octconv_kernel(
    const ushort* __restrict__ input,   // bf16 [NN+1][32] in d_ws (row NN = 0)
    const float* __restrict__ weights,  // [27][32][64] fp32
    const int*   __restrict__ neigh,    // [N][27]
    float*       __restrict__ out)      // [N][64]
{
  // Compact weights: [k][g][o] of 8-channel bf16 vectors, 16B each.
  // Measured conflict-free (R5: SQ_LDS_BANK_CONFLICT = 0).
  __shared__ ushort w_lds[KK * 4 * CO * 8];   // 110,592 B -> 16 waves/CU

  for (int i = threadIdx.x; i < KK * 4 * CO; i += THREADS) {
    const int k = i >> 8;
    const int g = (i >> 6) & 3;
    const int o = i & 63;
    const float* wp = weights + ((size_t)k * CI + g * 8) * CO + o;
    u16x8 w;
#pragma unroll
    for (int j = 0; j < 8; ++j) w[j] = f2bf_rne(wp[j * CO]);
    *(u16x8*)&w_lds[i * 8] = w;
  }

  const int lane = threadIdx.x & 63;
  const int wave = threadIdx.x >> 6;
  const int g    = lane >> 4;
  const int r16  = lane & 15;
  const int oct_base = blockIdx.x * OCT_PER_BLOCK + wave * 16;

  // Per-lane u32 byte offsets for all 27 gathers (invalid -> zero row NN).
  uint32_t voff[KK];
  {
    const int* __restrict__ nrow = neigh + (size_t)(oct_base + r16) * KK;
#pragma unroll
    for (int k = 0; k < KK; ++k) {
      const int idx = nrow[k];
      voff[k] = ((uint32_t)(idx < 0 ? NN : idx) << 6) + g * 16;
    }
  }

  __syncthreads();   // also drains vmcnt -> clean counter for the asm region

  f32x4 acc[4];
#pragma unroll
  for (int b = 0; b < 4; ++b) acc[b] = (f32x4){0.f, 0.f, 0.f, 0.f};

  const char* ibase = (const char*)input;
  const ushort* __restrict__ wfrag = &w_lds[g * (CO * 8) + r16 * 8];

  // Prologue: force 16 gathers in flight.
  i32x4 abuf[PF];
#pragma unroll
  for (int k = 0; k < PF; ++k) gload16(abuf[k], voff[k], ibase);

  // 27 taps, fully unrolled with constexpr K (counted vmcnt literals).
  run_taps(std::make_index_sequence<KK>{}, abuf, voff, ibase, wfrag, acc);

  // C/D layout: col = lane&15, row = (lane>>4)*4 + reg
  float* __restrict__ obase = out + (size_t)(oct_base + g * 4) * CO + r16;
#pragma unroll
  for (int rr = 0; rr < 4; ++rr)
#pragma unroll
    for (int b = 0; b < 4; ++b)
      obase[rr * CO + 16 * b] = acc[b][rr];
}

// Fallback (ws too small for bf16 copy): fp32 gather + inline cvt.
__global__ __launch_bounds__(THREADS, 4) void octconv_kernel_f32(
    const float* __restrict__ input, const float* __restrict__ weights,
    const int* __restrict__ neigh, float* __restrict__ out)
{
  __shared__ ushort w_lds[KK * 4 * CO * 8];
  for (int i = threadIdx.x; i < KK * 4 * CO; i += THREADS) {
    const int k = i >> 8;
    const int g = (i >> 6) & 3;
    const int o = i & 63;
    const float* wp = weights + ((size_t)k * CI + g * 8) * CO + o;
    u16x8 w;
#pragma unroll
    for (int j = 0; j < 8; ++j) w[j] = f2bf_rne(wp[j * CO]);
    *(u16x8*)&w_lds[i * 8] = w;
  }
  const int lane = threadIdx.x & 63;
  const int wave = threadIdx.x >> 6;
  const int g = lane >> 4, r16 = lane & 15;
  const int oct_base = blockIdx.x * OCT_PER_BLOCK + wave * 16;
  const int* __restrict__ nrow = neigh + (size_t)(oct_base + r16) * KK;
  __syncthreads();
  f32x4 acc[4];
#pragma unroll
  for (int b = 0; b < 4; ++b) acc[b] = (f32x4){0.f, 0.f, 0.f, 0.f};
#pragma unroll
  for (int k = 0; k < KK; ++k) {
    const int idx = nrow[k];
    const float* ip = input + (size_t)(idx < 0 ? 0 : idx) * CI + g * 8;
    f32x4 v0 = *(const f32x4*)ip, v1 = *(const f32x4*)(ip + 4);
    if (idx < 0) { v0 = (f32x4){0,0,0,0}; v1 = (f32x4){0,0,0,0}; }
    bf16x8 a;
    a[0]=(__bf16)v0[0]; a[1]=(__bf16)v0[1]; a[2]=(__bf16)v0[2]; a[3]=(__bf16)v0[3];
    a[4]=(__bf16)v1[0]; a[5]=(__bf16)v1[1]; a[6]=(__bf16)v1[2]; a[7]=(__bf16)v1[3];
    const ushort* wk = &w_lds[(k * 4 + g) * (CO * 8) + r16 * 8];
#pragma unroll
    for (int b = 0; b < 4; ++b) {
      const bf16x8 bf = *(const bf16x8*)(wk + b * 128);
      acc[b] = __builtin_amdgcn_mfma_f32_16x16x32_bf16(a, bf, acc[b], 0, 0, 0);
    }
  }
  float* obase = out + (size_t)(oct_base + g * 4) * CO + r16;
#pragma unroll
  for (int rr = 0; rr < 4; ++rr)
#pragma unroll
    for (int b = 0; b < 4; ++b)
      obase[rr * CO + 16 * b] = acc[b][rr];
}

extern "C" void kernel_launch(void* const* d_in, const int* in_sizes, int n_in,
                              void* d_out, int out_size, void* d_ws, size_t ws_size,
                              hipStream_t stream) {
  const float* input   = (const float*)d_in[0];
  const float* weights = (const float*)d_in[1];
  const int*   neigh   = (const int*)d_in[2];
  float*       out     = (float*)d_out;

  const size_t bf16_bytes = ((size_t)NN + 1) * CI * sizeof(ushort);  // 16 MiB + row
  dim3 grid(NN / OCT_PER_BLOCK);   // 1024 blocks

  if (ws_size >= bf16_bytes) {
    ushort* in_bf16 = (ushort*)d_ws;
    cvt_input_kernel<<<dim3((NN * CI) / 1024 + 1), 256, 0, stream>>>(input, in_bf16);
    octconv_kernel<<<grid, THREADS, 0, stream>>>(in_bf16, weights, neigh, out);
  } else {
    octconv_kernel_f32<<<grid, THREADS, 0, stream>>>(input, weights, neigh, out);
  }
}

// Round 7
// 117.319 us; speedup vs baseline: 1.0012x; 1.0012x over previous
//
#include <hip/hip_runtime.h>
#include <utility>

// OctreeConv: out[N,64] = sum_k gather_k(input)[N,32] @ W[k][32,64]
// Round 6: inline-asm forced gather pipeline. The compiler kept collapsing
// the software pipeline to ~4 deep (R3/R5: VGPR=88/52); here the 16-deep
// rotating buffer is built from asm-volatile global_load_dwordx4 + counted
// s_waitcnt vmcnt(N), with the consumed register pinned "+v" into the wait
// (rule #18) so MFMA cannot hoist above it. 16 waves/CU x 16 in flight.

typedef float  f32x4  __attribute__((ext_vector_type(4)));
typedef __bf16 bf16x8 __attribute__((ext_vector_type(8)));
typedef int    i32x4  __attribute__((ext_vector_type(4)));
typedef ushort u16x4  __attribute__((ext_vector_type(4)));
typedef ushort u16x8  __attribute__((ext_vector_type(8)));

#define NN 262144
#define CI 32
#define CO 64
#define KK 27
#define THREADS 1024
#define PF 16                 // forced prefetch depth (taps in flight)
#define OCT_PER_BLOCK 256     // 16 waves x 16 octants

__device__ __forceinline__ ushort f2bf_rne(float f) {
  union { float f; unsigned u; } v; v.f = f;
  unsigned u = v.u;
  u += 0x7FFFu + ((u >> 16) & 1u);
  return (ushort)(u >> 16);
}

// fp32 -> bf16 pre-pass; last block writes a zero row at index NN
// (gather target for invalid neighbors).
__global__ __launch_bounds__(256) void cvt_input_kernel(
    const float* __restrict__ in, ushort* __restrict__ out) {
  const int bid = blockIdx.x;
  if (bid == (NN * CI) / 1024) {
    if (threadIdx.x < 8) {
      u16x4 z = {0, 0, 0, 0};
      *(u16x4*)(out + (size_t)NN * CI + threadIdx.x * 4) = z;
    }
    return;
  }
  const int i = (bid * 256 + threadIdx.x) * 4;
  f32x4 v = *(const f32x4*)(in + i);
  u16x4 o;
  o[0] = f2bf_rne(v[0]); o[1] = f2bf_rne(v[1]);
  o[2] = f2bf_rne(v[2]); o[3] = f2bf_rne(v[3]);
  *(u16x4*)(out + i) = o;
}

// asm gather: 16B load, base(SGPR pair) + u32 voffset. asm volatile keeps
// issue order and prevents the compiler from sinking/shrinking the pipeline.
__device__ __forceinline__ void gload16(i32x4& dst, uint32_t voff,
                                        const char* base) {
  asm volatile("global_load_dwordx4 %0, %1, %2"
               : "=v"(dst)
               : "v"(voff), "s"(base));
}

// counted wait; "+v" on the consumed value makes every later use (the MFMA)
// data-dependent on the wait -> cannot be scheduled above it.
template <int N>
__device__ __forceinline__ void wait_vmcnt_pin(i32x4& v) {
  asm volatile("s_waitcnt vmcnt(%1)" : "+v"(v) : "n"(N));
}

template <int K>
__device__ __forceinline__ void tap(i32x4 (&abuf)[PF],
                                    const uint32_t (&voff)[KK],
                                    const char* ibase,
                                    const ushort* __restrict__ wfrag,
                                    f32x4 (&acc)[4]) {
  constexpr int NWAIT = (PF - 1 < KK - 1 - K) ? (PF - 1) : (KK - 1 - K);
  wait_vmcnt_pin<NWAIT>(abuf[K % PF]);
  const bf16x8 a = __builtin_bit_cast(bf16x8, abuf[K % PF]);
#pragma unroll
  for (int b = 0; b < 4; ++b) {
    const bf16x8 bf = *(const bf16x8*)(wfrag + K * 2048 + b * 128);
    acc[b] = __builtin_amdgcn_mfma_f32_16x16x32_bf16(a, bf, acc[b], 0, 0, 0);
  }
  if constexpr (K + PF < KK)
    gload16(abuf[K % PF], voff[K + PF], ibase);
}

template <size_t... Ks>
__device__ __forceinline__ void run_taps(std::index_sequence<Ks...>,
                                         i32x4 (&abuf)[PF],
                                         const uint32_t (&voff)[KK],
                                         const char* ibase,
                                         const ushort* __restrict__ wfrag,
                                         f32x4 (&acc)[4]) {
  (tap<(int)Ks>(abuf, voff, ibase, wfrag, acc), ...);
}

__global__ __launch_bounds__(THREADS, 4) void octconv_kernel(
    const ushort* __restrict__ input,   // bf16 [NN+1][32] in d_ws (row NN = 0)
    const float* __restrict__ weights,  // [27][32][64] fp32
    const int*   __restrict__ neigh,    // [N][27]
    float*       __restrict__ out)      // [N][64]
{
  // Compact weights: [k][g][o] of 8-channel bf16 vectors, 16B each.
  // Measured conflict-free (R5: SQ_LDS_BANK_CONFLICT = 0).
  __shared__ ushort w_lds[KK * 4 * CO * 8];   // 110,592 B -> 16 waves/CU

  for (int i = threadIdx.x; i < KK * 4 * CO; i += THREADS) {
    const int k = i >> 8;
    const int g = (i >> 6) & 3;
    const int o = i & 63;
    const float* wp = weights + ((size_t)k * CI + g * 8) * CO + o;
    u16x8 w;
#pragma unroll
    for (int j = 0; j < 8; ++j) w[j] = f2bf_rne(wp[j * CO]);
    *(u16x8*)&w_lds[i * 8] = w;
  }

  const int lane = threadIdx.x & 63;
  const int wave = threadIdx.x >> 6;
  const int g    = lane >> 4;
  const int r16  = lane & 15;
  const int oct_base = blockIdx.x * OCT_PER_BLOCK + wave * 16;

  // Per-lane u32 byte offsets for all 27 gathers (invalid -> zero row NN).
  uint32_t voff[KK];
  {
    const int* __restrict__ nrow = neigh + (size_t)(oct_base + r16) * KK;
#pragma unroll
    for (int k = 0; k < KK; ++k) {
      const int idx = nrow[k];
      voff[k] = ((uint32_t)(idx < 0 ? NN : idx) << 6) + g * 16;
    }
  }

  __syncthreads();   // also drains vmcnt -> clean counter for the asm region

  f32x4 acc[4];
#pragma unroll
  for (int b = 0; b < 4; ++b) acc[b] = (f32x4){0.f, 0.f, 0.f, 0.f};

  const char* ibase = (const char*)input;
  const ushort* __restrict__ wfrag = &w_lds[g * (CO * 8) + r16 * 8];

  // Prologue: force 16 gathers in flight.
  i32x4 abuf[PF];
#pragma unroll
  for (int k = 0; k < PF; ++k) gload16(abuf[k], voff[k], ibase);

  // 27 taps, fully unrolled with constexpr K (counted vmcnt literals).
  run_taps(std::make_index_sequence<KK>{}, abuf, voff, ibase, wfrag, acc);

  // C/D layout: col = lane&15, row = (lane>>4)*4 + reg
  float* __restrict__ obase = out + (size_t)(oct_base + g * 4) * CO + r16;
#pragma unroll
  for (int rr = 0; rr < 4; ++rr)
#pragma unroll
    for (int b = 0; b < 4; ++b)
      obase[rr * CO + 16 * b] = acc[b][rr];
}

// Fallback (ws too small for bf16 copy): fp32 gather + inline cvt.
__global__ __launch_bounds__(THREADS, 4) void octconv_kernel_f32(
    const float* __restrict__ input, const float* __restrict__ weights,
    const int* __restrict__ neigh, float* __restrict__ out)
{
  __shared__ ushort w_lds[KK * 4 * CO * 8];
  for (int i = threadIdx.x; i < KK * 4 * CO; i += THREADS) {
    const int k = i >> 8;
    const int g = (i >> 6) & 3;
    const int o = i & 63;
    const float* wp = weights + ((size_t)k * CI + g * 8) * CO + o;
    u16x8 w;
#pragma unroll
    for (int j = 0; j < 8; ++j) w[j] = f2bf_rne(wp[j * CO]);
    *(u16x8*)&w_lds[i * 8] = w;
  }
  const int lane = threadIdx.x & 63;
  const int wave = threadIdx.x >> 6;
  const int g = lane >> 4, r16 = lane & 15;
  const int oct_base = blockIdx.x * OCT_PER_BLOCK + wave * 16;
  const int* __restrict__ nrow = neigh + (size_t)(oct_base + r16) * KK;
  __syncthreads();
  f32x4 acc[4];
#pragma unroll
  for (int b = 0; b < 4; ++b) acc[b] = (f32x4){0.f, 0.f, 0.f, 0.f};
#pragma unroll
  for (int k = 0; k < KK; ++k) {
    const int idx = nrow[k];
    const float* ip = input + (size_t)(idx < 0 ? 0 : idx) * CI + g * 8;
    f32x4 v0 = *(const f32x4*)ip, v1 = *(const f32x4*)(ip + 4);
    if (idx < 0) { v0 = (f32x4){0,0,0,0}; v1 = (f32x4){0,0,0,0}; }
    bf16x8 a;
    a[0]=(__bf16)v0[0]; a[1]=(__bf16)v0[1]; a[2]=(__bf16)v0[2]; a[3]=(__bf16)v0[3];
    a[4]=(__bf16)v1[0]; a[5]=(__bf16)v1[1]; a[6]=(__bf16)v1[2]; a[7]=(__bf16)v1[3];
    const ushort* wk = &w_lds[(k * 4 + g) * (CO * 8) + r16 * 8];
#pragma unroll
    for (int b = 0; b < 4; ++b) {
      const bf16x8 bf = *(const bf16x8*)(wk + b * 128);
      acc[b] = __builtin_amdgcn_mfma_f32_16x16x32_bf16(a, bf, acc[b], 0, 0, 0);
    }
  }
  float* obase = out + (size_t)(oct_base + g * 4) * CO + r16;
#pragma unroll
  for (int rr = 0; rr < 4; ++rr)
#pragma unroll
    for (int b = 0; b < 4; ++b)
      obase[rr * CO + 16 * b] = acc[b][rr];
}

extern "C" void kernel_launch(void* const* d_in, const int* in_sizes, int n_in,
                              void* d_out, int out_size, void* d_ws, size_t ws_size,
                              hipStream_t stream) {
  const float* input   = (const float*)d_in[0];
  const float* weights = (const float*)d_in[1];
  const int*   neigh   = (const int*)d_in[2];
  float*       out     = (float*)d_out;

  const size_t bf16_bytes = ((size_t)NN + 1) * CI * sizeof(ushort);  // 16 MiB + row
  dim3 grid(NN / OCT_PER_BLOCK);   // 1024 blocks

  if (ws_size >= bf16_bytes) {
    ushort* in_bf16 = (ushort*)d_ws;
    cvt_input_kernel<<<dim3((NN * CI) / 1024 + 1), 256, 0, stream>>>(input, in_bf16);
    octconv_kernel<<<grid, THREADS, 0, stream>>>(in_bf16, weights, neigh, out);
  } else {
    octconv_kernel_f32<<<grid, THREADS, 0, stream>>>(input, weights, neigh, out);
  }
}

// Round 10
// 113.575 us; speedup vs baseline: 1.0342x; 1.0330x over previous
//
#include <hip/hip_runtime.h>

// OctreeConv: out[N,64] = sum_k gather_k(input)[N,32] @ W[k][32,64]
// Round 9: coalescing A/B test, compiler-correct. Gather lane-map changed to
// quad-coalesced (row=l>>2, chunk=l&3: 4 consecutive lanes = one 64B line);
// the MFMA A-fragment (row=l&15, chunk=l>>4) is recovered in-register via
// 4x ds_bpermute (builtin -> compiler handles all hazards). No inline asm:
// R6/R8 showed asm-opaque VMEM defeats regalloc/waitcnt insertion (spilled
// not-yet-returned loads -> NaN). Base structure = R5 (106us, passed).

typedef float  f32x4  __attribute__((ext_vector_type(4)));
typedef __bf16 bf16x8 __attribute__((ext_vector_type(8)));
typedef int    i32x4  __attribute__((ext_vector_type(4)));
typedef ushort u16x4  __attribute__((ext_vector_type(4)));
typedef ushort u16x8  __attribute__((ext_vector_type(8)));

#define NN 262144
#define CI 32
#define CO 64
#define KK 27
#define THREADS 1024
#define PF 8                  // rotating A-buffer depth (compiler may shrink)
#define OCT_PER_BLOCK 256     // 16 waves x 16 octants

__device__ __forceinline__ ushort f2bf_rne(float f) {
  union { float f; unsigned u; } v; v.f = f;
  unsigned u = v.u;
  u += 0x7FFFu + ((u >> 16) & 1u);
  return (ushort)(u >> 16);
}

// fp32 -> bf16 pre-pass; last block writes a zero row at index NN
// (gather target for invalid neighbors).
__global__ __launch_bounds__(256) void cvt_input_kernel(
    const float* __restrict__ in, ushort* __restrict__ out) {
  const int bid = blockIdx.x;
  if (bid == (NN * CI) / 1024) {
    if (threadIdx.x < 8) {
      u16x4 z = {0, 0, 0, 0};
      *(u16x4*)(out + (size_t)NN * CI + threadIdx.x * 4) = z;
    }
    return;
  }
  const int i = (bid * 256 + threadIdx.x) * 4;
  f32x4 v = *(const f32x4*)(in + i);
  u16x4 o;
  o[0] = f2bf_rne(v[0]); o[1] = f2bf_rne(v[1]);
  o[2] = f2bf_rne(v[2]); o[3] = f2bf_rne(v[3]);
  *(u16x4*)(out + i) = o;
}

__global__ __launch_bounds__(THREADS, 4) void octconv_kernel(
    const ushort* __restrict__ input,   // bf16 [NN+1][32] in d_ws (row NN = 0)
    const float* __restrict__ weights,  // [27][32][64] fp32
    const int*   __restrict__ neigh,    // [N][27]
    float*       __restrict__ out)      // [N][64]
{
  // Weights: [k][g][o] 16B vectors (R5-measured conflict-free), 110,592 B.
  __shared__ ushort w_lds[KK * 4 * CO * 8];

  for (int i = threadIdx.x; i < KK * 4 * CO; i += THREADS) {
    const int k = i >> 8;
    const int g = (i >> 6) & 3;
    const int o = i & 63;
    const float* wp = weights + ((size_t)k * CI + g * 8) * CO + o;
    u16x8 w;
#pragma unroll
    for (int j = 0; j < 8; ++j) w[j] = f2bf_rne(wp[j * CO]);
    *(u16x8*)&w_lds[i * 8] = w;
  }

  const int lane = threadIdx.x & 63;
  const int wave = threadIdx.x >> 6;
  const int g    = lane >> 4;   // fragment chunk (MFMA layout)
  const int r16  = lane & 15;   // fragment row   (MFMA layout)
  const int grow = lane >> 2;   // gather row     (quad-coalesced layout)
  const int gch  = lane & 3;    // gather chunk
  const int oct_base = blockIdx.x * OCT_PER_BLOCK + wave * 16;

  // bpermute byte-index: reader lane l pulls the i32x4 gathered by lane
  // (l&15)*4 + (l>>4)  (that lane holds row=l&15, channels [ (l>>4)*8 .. +8 ))
  const int src_b = ((r16 << 2) | g) << 2;

  // Per-lane u32 byte offsets: row = neigh[oct_base + grow][k], chunk gch.
  // (4 lanes per quad load the same nrow address -> broadcast, cheap.)
  uint32_t voff[KK];
  {
    const int* __restrict__ nrow = neigh + (size_t)(oct_base + grow) * KK;
#pragma unroll
    for (int k = 0; k < KK; ++k) {
      const int idx = nrow[k];
      voff[k] = ((uint32_t)(idx < 0 ? NN : idx) << 6) + gch * 16;
    }
  }

  __syncthreads();

  f32x4 acc[4];
#pragma unroll
  for (int b = 0; b < 4; ++b) acc[b] = (f32x4){0.f, 0.f, 0.f, 0.f};

  const char* __restrict__ ibase = (const char*)input;
  const ushort* __restrict__ wfrag = &w_lds[g * (CO * 8) + r16 * 8];

  // Rotating gather pipeline (plain loads; compiler manages waitcnts).
  i32x4 abuf[PF];
#pragma unroll
  for (int k = 0; k < PF; ++k)
    abuf[k] = *(const i32x4*)(ibase + voff[k]);

#pragma unroll
  for (int k = 0; k < KK; ++k) {
    const i32x4 v = abuf[k % PF];
    // in-register lane permutation: gather layout -> MFMA A-fragment layout
    i32x4 p;
    p[0] = __builtin_amdgcn_ds_bpermute(src_b, v[0]);
    p[1] = __builtin_amdgcn_ds_bpermute(src_b, v[1]);
    p[2] = __builtin_amdgcn_ds_bpermute(src_b, v[2]);
    p[3] = __builtin_amdgcn_ds_bpermute(src_b, v[3]);
    const bf16x8 a = __builtin_bit_cast(bf16x8, p);
#pragma unroll
    for (int b = 0; b < 4; ++b) {
      const bf16x8 bf = *(const bf16x8*)(wfrag + k * 2048 + b * 128);
      acc[b] = __builtin_amdgcn_mfma_f32_16x16x32_bf16(a, bf, acc[b], 0, 0, 0);
    }
    if (k + PF < KK)
      abuf[k % PF] = *(const i32x4*)(ibase + voff[k + PF]);
  }

  // C/D layout: col = lane&15, row = (lane>>4)*4 + reg
  float* __restrict__ obase = out + (size_t)(oct_base + g * 4) * CO + r16;
#pragma unroll
  for (int rr = 0; rr < 4; ++rr)
#pragma unroll
    for (int b = 0; b < 4; ++b)
      obase[rr * CO + 16 * b] = acc[b][rr];
}

// Fallback (ws too small for bf16 copy): fp32 gather + inline cvt.
__global__ __launch_bounds__(THREADS, 4) void octconv_kernel_f32(
    const float* __restrict__ input, const float* __restrict__ weights,
    const int* __restrict__ neigh, float* __restrict__ out)
{
  __shared__ ushort w_lds[KK * 4 * CO * 8];
  for (int i = threadIdx.x; i < KK * 4 * CO; i += THREADS) {
    const int k = i >> 8;
    const int g = (i >> 6) & 3;
    const int o = i & 63;
    const float* wp = weights + ((size_t)k * CI + g * 8) * CO + o;
    u16x8 w;
#pragma unroll
    for (int j = 0; j < 8; ++j) w[j] = f2bf_rne(wp[j * CO]);
    *(u16x8*)&w_lds[i * 8] = w;
  }
  const int lane = threadIdx.x & 63;
  const int wave = threadIdx.x >> 6;
  const int g = lane >> 4, r16 = lane & 15;
  const int oct_base = blockIdx.x * OCT_PER_BLOCK + wave * 16;
  const int* __restrict__ nrow = neigh + (size_t)(oct_base + r16) * KK;
  __syncthreads();
  f32x4 acc[4];
#pragma unroll
  for (int b = 0; b < 4; ++b) acc[b] = (f32x4){0.f, 0.f, 0.f, 0.f};
#pragma unroll
  for (int k = 0; k < KK; ++k) {
    const int idx = nrow[k];
    const float* ip = input + (size_t)(idx < 0 ? 0 : idx) * CI + g * 8;
    f32x4 v0 = *(const f32x4*)ip, v1 = *(const f32x4*)(ip + 4);
    if (idx < 0) { v0 = (f32x4){0,0,0,0}; v1 = (f32x4){0,0,0,0}; }
    bf16x8 a;
    a[0]=(__bf16)v0[0]; a[1]=(__bf16)v0[1]; a[2]=(__bf16)v0[2]; a[3]=(__bf16)v0[3];
    a[4]=(__bf16)v1[0]; a[5]=(__bf16)v1[1]; a[6]=(__bf16)v1[2]; a[7]=(__bf16)v1[3];
    const ushort* wk = &w_lds[(k * 4 + g) * (CO * 8) + r16 * 8];
#pragma unroll
    for (int b = 0; b < 4; ++b) {
      const bf16x8 bf = *(const bf16x8*)(wk + b * 128);
      acc[b] = __builtin_amdgcn_mfma_f32_16x16x32_bf16(a, bf, acc[b], 0, 0, 0);
    }
  }
  float* obase = out + (size_t)(oct_base + g * 4) * CO + r16;
#pragma unroll
  for (int rr = 0; rr < 4; ++rr)
#pragma unroll
    for (int b = 0; b < 4; ++b)
      obase[rr * CO + 16 * b] = acc[b][rr];
}

extern "C" void kernel_launch(void* const* d_in, const int* in_sizes, int n_in,
                              void* d_out, int out_size, void* d_ws, size_t ws_size,
                              hipStream_t stream) {
  const float* input   = (const float*)d_in[0];
  const float* weights = (const float*)d_in[1];
  const int*   neigh   = (const int*)d_in[2];
  float*       out     = (float*)d_out;

  const size_t bf16_bytes = ((size_t)NN + 1) * CI * sizeof(ushort);  // 16 MiB + row
  dim3 grid(NN / OCT_PER_BLOCK);   // 1024 blocks

  if (ws_size >= bf16_bytes) {
    ushort* in_bf16 = (ushort*)d_ws;
    cvt_input_kernel<<<dim3((NN * CI) / 1024 + 1), 256, 0, stream>>>(input, in_bf16);
    octconv_kernel<<<grid, THREADS, 0, stream>>>(in_bf16, weights, neigh, out);
  } else {
    octconv_kernel_f32<<<grid, THREADS, 0, stream>>>(input, weights, neigh, out);
  }
}